// Round 1
// baseline (1564.431 us; speedup 1.0000x reference)
//
#include <hip/hip_runtime.h>
#include <math.h>

#define NN 10000
#define NE 160000
#define FDIM 128
#define NRBF 20
#define PI_F 3.14159265358979323846f

// ---------------------------------------------------------------------------
// Edge geometry + src histogram
// ---------------------------------------------------------------------------
__global__ void edge_geom_kernel(const float* __restrict__ xyz, const int* __restrict__ nbr,
                                 float* __restrict__ unit, float* __restrict__ rbf,
                                 float* __restrict__ env, int* __restrict__ counts)
{
    int e = blockIdx.x * blockDim.x + threadIdx.x;
    if (e >= NE) return;
    int s = nbr[2 * e], d = nbr[2 * e + 1];
    float dx = xyz[3 * d + 0] - xyz[3 * s + 0];
    float dy = xyz[3 * d + 1] - xyz[3 * s + 1];
    float dz = xyz[3 * d + 2] - xyz[3 * s + 2];
    float dist = sqrtf(dx * dx + dy * dy + dz * dz);
    float inv = 1.0f / dist;
    unit[3 * e + 0] = dx * inv;
    unit[3 * e + 1] = dy * inv;
    unit[3 * e + 2] = dz * inv;
    const float c = PI_F / 5.0f;
#pragma unroll
    for (int k = 0; k < NRBF; k++)
        rbf[NRBF * e + k] = sinf((float)(k + 1) * c * dist) * inv;
    env[e] = (dist < 5.0f) ? 0.5f * (cosf(c * dist) + 1.0f) : 0.0f;
    atomicAdd(&counts[s], 1);
}

// ---------------------------------------------------------------------------
// Single-block exclusive scan over counts -> offsets (N+1)
// ---------------------------------------------------------------------------
__global__ void scan_kernel(const int* __restrict__ counts, int* __restrict__ offsets)
{
    __shared__ int sd[1024];
    __shared__ int carry;
    if (threadIdx.x == 0) carry = 0;
    __syncthreads();
    for (int base = 0; base < NN; base += 1024) {
        int i = base + threadIdx.x;
        int v = (i < NN) ? counts[i] : 0;
        sd[threadIdx.x] = v;
        __syncthreads();
        for (int off = 1; off < 1024; off <<= 1) {
            int t = (threadIdx.x >= off) ? sd[threadIdx.x - off] : 0;
            __syncthreads();
            sd[threadIdx.x] += t;
            __syncthreads();
        }
        if (i < NN) offsets[i] = carry + sd[threadIdx.x] - v;
        __syncthreads();
        if (threadIdx.x == 0) carry += sd[1023];
        __syncthreads();
    }
    if (threadIdx.x == 0) offsets[NN] = carry;
}

__global__ void fill_kernel(const int* __restrict__ nbr, const int* __restrict__ offsets,
                            int* __restrict__ cnt2, int* __restrict__ eidx)
{
    int e = blockIdx.x * blockDim.x + threadIdx.x;
    if (e >= NE) return;
    int s = nbr[2 * e];
    int p = offsets[s] + atomicAdd(&cnt2[s], 1);
    eidx[p] = e;
}

// ---------------------------------------------------------------------------
// Concat two (N,128) -> (N,256)
// ---------------------------------------------------------------------------
__global__ void concat_kernel(const float* __restrict__ A, const float* __restrict__ B,
                              float* __restrict__ C)
{
    int idx = blockIdx.x * blockDim.x + threadIdx.x;
    if (idx >= NN * 256) return;
    int n = idx >> 8, j = idx & 255;
    C[idx] = (j < 128) ? A[n * 128 + j] : B[n * 128 + (j - 128)];
}

// ---------------------------------------------------------------------------
// fp32 GEMM: C[M,N] = act(A[M,K] @ W[K,N] + bias[N]); ACT=1 -> silu
// BM=BN=64, BK=16, 256 threads, 4x4 micro-tile. N,K multiples of required tiles.
// ---------------------------------------------------------------------------
template <int ACT>
__global__ __launch_bounds__(256) void gemm_kernel(const float* __restrict__ A,
                                                   const float* __restrict__ W,
                                                   const float* __restrict__ bias,
                                                   float* __restrict__ C,
                                                   int M, int K, int N)
{
    __shared__ __align__(16) float As[16][68];
    __shared__ __align__(16) float Ws[16][64];
    int tid = threadIdx.x;
    int tx = tid & 15, ty = tid >> 4;
    int row0 = blockIdx.y * 64, col0 = blockIdx.x * 64;
    float acc[4][4] = {};
    int la_r = tid >> 2;          // 0..63
    int la_c = (tid & 3) * 4;     // 0,4,8,12
    int lw_r = tid >> 4;          // 0..15
    int lw_c = (tid & 15) * 4;    // 0..60

    for (int k0 = 0; k0 < K; k0 += 16) {
        int ar = row0 + la_r;
        float4 av = make_float4(0.f, 0.f, 0.f, 0.f);
        if (ar < M) av = *(const float4*)&A[(size_t)ar * K + k0 + la_c];
        As[la_c + 0][la_r] = av.x;
        As[la_c + 1][la_r] = av.y;
        As[la_c + 2][la_r] = av.z;
        As[la_c + 3][la_r] = av.w;
        float4 wv = *(const float4*)&W[(size_t)(k0 + lw_r) * N + col0 + lw_c];
        *(float4*)&Ws[lw_r][lw_c] = wv;
        __syncthreads();
#pragma unroll
        for (int k = 0; k < 16; k++) {
            float ar4[4], wr4[4];
#pragma unroll
            for (int i = 0; i < 4; i++) ar4[i] = As[k][ty * 4 + i];
#pragma unroll
            for (int j = 0; j < 4; j++) wr4[j] = Ws[k][tx * 4 + j];
#pragma unroll
            for (int i = 0; i < 4; i++)
#pragma unroll
                for (int j = 0; j < 4; j++) acc[i][j] += ar4[i] * wr4[j];
        }
        __syncthreads();
    }
#pragma unroll
    for (int i = 0; i < 4; i++) {
        int r = row0 + ty * 4 + i;
        if (r >= M) continue;
#pragma unroll
        for (int j = 0; j < 4; j++) {
            int c = col0 + tx * 4 + j;
            float v = acc[i][j] + bias[c];
            if (ACT) v = v / (1.0f + expf(-v));
            C[(size_t)r * N + c] = v;
        }
    }
}

// ---------------------------------------------------------------------------
// Gather message kernel: one block per node (128 threads = one per feature).
// Computes w_s on the fly from LDS-cached dist_W; accumulates all segment sums
// for this src node in registers. V/Vbar double-buffered.
// ---------------------------------------------------------------------------
__global__ __launch_bounds__(128) void gather_kernel(
    const int* __restrict__ offsets, const int* __restrict__ eidx,
    const int* __restrict__ nbr,
    const float* __restrict__ unit, const float* __restrict__ rbf,
    const float* __restrict__ env,
    const float* __restrict__ phi,
    const float* __restrict__ distW, const float* __restrict__ distb,
    const float* __restrict__ Vold, const float* __restrict__ Vbold,
    float* __restrict__ H, float* __restrict__ Sbar,
    float* __restrict__ Vnew, float* __restrict__ Vbnew)
{
    int n = blockIdx.x;
    int f = threadIdx.x;
    __shared__ __align__(16) float sW[NRBF * 640];
    for (int i = f; i < NRBF * 640 / 4; i += 128)
        ((float4*)sW)[i] = ((const float4*)distW)[i];
    float b0 = distb[f], b1 = distb[128 + f], b2 = distb[256 + f],
          b3 = distb[384 + f], b4 = distb[512 + f];
    __syncthreads();

    float accH = 0.f, accS = 0.f;
    float accV0 = 0.f, accV1 = 0.f, accV2 = 0.f;
    float accB0 = 0.f, accB1 = 0.f, accB2 = 0.f;
    int e0 = offsets[n], e1 = offsets[n + 1];
    for (int ii = e0; ii < e1; ++ii) {
        int e = eidx[ii];
        int d = nbr[2 * e + 1];
        float ux = unit[3 * e + 0], uy = unit[3 * e + 1], uz = unit[3 * e + 2];
        float ev = env[e];
        float r[NRBF];
#pragma unroll
        for (int k = 0; k < NRBF / 4; k++) {
            float4 rv = *(const float4*)&rbf[NRBF * e + 4 * k];
            r[4 * k + 0] = rv.x; r[4 * k + 1] = rv.y;
            r[4 * k + 2] = rv.z; r[4 * k + 3] = rv.w;
        }
        float w0 = b0, w1 = b1, w2 = b2, w3 = b3, w4 = b4;
#pragma unroll
        for (int k = 0; k < NRBF; k++) {
            float rk = r[k];
            const float* wr = &sW[k * 640];
            w0 += rk * wr[f];
            w1 += rk * wr[128 + f];
            w2 += rk * wr[256 + f];
            w3 += rk * wr[384 + f];
            w4 += rk * wr[512 + f];
        }
        const float* ph = &phi[(size_t)d * 640];
        float i0 = ph[f] * w0 * ev;
        float i1 = ph[128 + f] * w1 * ev;
        float i2 = ph[256 + f] * w2 * ev;
        float i3 = ph[384 + f] * w3 * ev;
        float i4 = ph[512 + f] * w4 * ev;
        accH += i1;
        accS += i3;
        const float* vd  = &Vold[(size_t)d * 384 + f * 3];
        const float* vbd = &Vbold[(size_t)d * 384 + f * 3];
        accV0 += i2 * ux + i0 * vd[0];
        accV1 += i2 * uy + i0 * vd[1];
        accV2 += i2 * uz + i0 * vd[2];
        accB0 += i2 * ux + i4 * vbd[0];
        accB1 += i2 * uy + i4 * vbd[1];
        accB2 += i2 * uz + i4 * vbd[2];
    }
    H[n * 128 + f] += accH;
    Sbar[n * 128 + f] += accS;
    const float* vo  = &Vold[(size_t)n * 384 + f * 3];
    const float* vbo = &Vbold[(size_t)n * 384 + f * 3];
    float* vn  = &Vnew[(size_t)n * 384 + f * 3];
    float* vbn = &Vbnew[(size_t)n * 384 + f * 3];
    vn[0] = vo[0] + accV0; vn[1] = vo[1] + accV1; vn[2] = vo[2] + accV2;
    vbn[0] = vbo[0] + accB0; vbn[1] = vbo[1] + accB1; vbn[2] = vbo[2] + accB2;
}

// ---------------------------------------------------------------------------
// u_v/v_v einsum + v_norm + dot.  4 nodes per block, 128 threads (g).
// u_v[n,g,d] = sum_f V[n,f,d] * U[f,g]
// ---------------------------------------------------------------------------
__global__ __launch_bounds__(128) void uv_kernel(const float* __restrict__ V,
                                                 const float* __restrict__ U,
                                                 const float* __restrict__ Vm,
                                                 float* __restrict__ u_v,
                                                 float* __restrict__ vnorm,
                                                 float* __restrict__ dotb)
{
    int g = threadIdx.x;
    int n0 = blockIdx.x * 4;
    __shared__ float sV[4 * 384];
    for (int i = g; i < 4 * 384; i += 128) {
        int nn = i / 384, rem = i % 384;
        int node = n0 + nn;
        sV[i] = (node < NN) ? V[(size_t)node * 384 + rem] : 0.f;
    }
    __syncthreads();
    float ua[4][3] = {}, va[4][3] = {};
    for (int ff = 0; ff < 128; ++ff) {
        float uf = U[ff * 128 + g];
        float vf = Vm[ff * 128 + g];
#pragma unroll
        for (int nn = 0; nn < 4; nn++) {
            float v0 = sV[nn * 384 + ff * 3 + 0];
            float v1 = sV[nn * 384 + ff * 3 + 1];
            float v2 = sV[nn * 384 + ff * 3 + 2];
            ua[nn][0] += v0 * uf; ua[nn][1] += v1 * uf; ua[nn][2] += v2 * uf;
            va[nn][0] += v0 * vf; va[nn][1] += v1 * vf; va[nn][2] += v2 * vf;
        }
    }
#pragma unroll
    for (int nn = 0; nn < 4; nn++) {
        int node = n0 + nn;
        if (node >= NN) continue;
        float d = ua[nn][0] * va[nn][0] + ua[nn][1] * va[nn][1] + ua[nn][2] * va[nn][2];
        float vn = sqrtf(va[nn][0] * va[nn][0] + va[nn][1] * va[nn][1] +
                         va[nn][2] * va[nn][2] + 1e-15f);
        u_v[(size_t)node * 384 + g * 3 + 0] = ua[nn][0];
        u_v[(size_t)node * 384 + g * 3 + 1] = ua[nn][1];
        u_v[(size_t)node * 384 + g * 3 + 2] = ua[nn][2];
        vnorm[node * 128 + g] = vn;
        dotb[node * 128 + g] = d;
    }
}

// ---------------------------------------------------------------------------
// Final per-layer update: H += a1*dot + a2 ; V += a0*u_v
// ---------------------------------------------------------------------------
__global__ void final_update_kernel(const float* __restrict__ a,
                                    const float* __restrict__ dotb,
                                    const float* __restrict__ u_v,
                                    float* __restrict__ H, float* __restrict__ Vbuf)
{
    int idx = blockIdx.x * blockDim.x + threadIdx.x;
    if (idx >= NN * 128) return;
    int n = idx >> 7, g = idx & 127;
    float a0 = a[n * 384 + g];
    float a1 = a[n * 384 + 128 + g];
    float a2 = a[n * 384 + 256 + g];
    H[idx] += a1 * dotb[idx] + a2;
    float* vp = &Vbuf[(size_t)n * 384 + g * 3];
    const float* up = &u_v[(size_t)n * 384 + g * 3];
    vp[0] += a0 * up[0];
    vp[1] += a0 * up[1];
    vp[2] += a0 * up[2];
}

// ---------------------------------------------------------------------------
extern "C" void kernel_launch(void* const* d_in, const int* in_sizes, int n_in,
                              void* d_out, int out_size, void* d_ws, size_t ws_size,
                              hipStream_t stream)
{
    const float* xyz    = (const float*)d_in[0];
    const int*   nbr    = (const int*)d_in[1];
    const float* H_in   = (const float*)d_in[3];
    const float* msgW1  = (const float*)d_in[4];
    const float* msgb1  = (const float*)d_in[5];
    const float* msgW2  = (const float*)d_in[6];
    const float* msgb2  = (const float*)d_in[7];
    const float* distW  = (const float*)d_in[8];
    const float* distb  = (const float*)d_in[9];
    const float* updU   = (const float*)d_in[10];
    const float* updV   = (const float*)d_in[11];
    const float* updW1  = (const float*)d_in[12];
    const float* updb1  = (const float*)d_in[13];
    const float* updW2  = (const float*)d_in[14];
    const float* updb2  = (const float*)d_in[15];

    float* out  = (float*)d_out;
    float* H    = out;                 // N*128
    float* Vout = out + NN * 128;      // N*384

    // ---- workspace carve (floats) ----
    float* f = (float*)d_ws;
    float* Va   = f; f += NN * 384;
    float* Vb   = f; f += NN * 384;
    float* Vba  = f; f += NN * 384;
    float* Vbb  = f; f += NN * 384;
    float* Sbar = f; f += NN * 128;
    float* Scat = f; f += NN * 256;
    float* X1   = f; f += NN * 256;
    float* phi  = f; f += NN * 640;    // aliased below after gather consumes it
    float* u_v  = f; f += NN * 384;
    float* unit = f; f += NE * 3;
    float* rbf  = f; f += NE * NRBF;
    float* env  = f; f += NE;
    int* ip = (int*)f;
    int* counts  = ip; ip += NN;
    int* offsets = ip; ip += NN + 1;
    int* cnt2    = ip; ip += NN;
    int* eidx    = ip; ip += NE;
    // aliases into dead phi region (phi dead after gather each layer)
    float* vnorm = phi;
    float* dotb  = phi + NN * 128;
    float* abuf  = phi + NN * 256;     // N*384

    // ---- init ----
    hipMemsetAsync(counts, 0, NN * sizeof(int), stream);
    hipMemsetAsync(cnt2, 0, NN * sizeof(int), stream);
    hipMemsetAsync(Va, 0, (size_t)NN * 384 * sizeof(float), stream);
    hipMemsetAsync(Vba, 0, (size_t)NN * 384 * sizeof(float), stream);
    hipMemsetAsync(Sbar, 0, (size_t)NN * 128 * sizeof(float), stream);
    hipMemcpyAsync(H, H_in, (size_t)NN * 128 * sizeof(float),
                   hipMemcpyDeviceToDevice, stream);

    // ---- edge geometry + CSR ----
    edge_geom_kernel<<<(NE + 255) / 256, 256, 0, stream>>>(xyz, nbr, unit, rbf, env, counts);
    scan_kernel<<<1, 1024, 0, stream>>>(counts, offsets);
    fill_kernel<<<(NE + 255) / 256, 256, 0, stream>>>(nbr, offsets, cnt2, eidx);

    for (int l = 0; l < 3; ++l) {
        const float* W1 = msgW1 + (size_t)l * 256 * 256;
        const float* b1 = msgb1 + (size_t)l * 256;
        const float* W2 = msgW2 + (size_t)l * 256 * 640;
        const float* b2 = msgb2 + (size_t)l * 640;
        const float* dW = distW + (size_t)l * NRBF * 640;
        const float* db = distb + (size_t)l * 640;
        const float* Ul = updU + (size_t)l * 128 * 128;
        const float* Vl = updV + (size_t)l * 128 * 128;
        const float* uW1 = updW1 + (size_t)l * 256 * 128;
        const float* ub1 = updb1 + (size_t)l * 128;
        const float* uW2 = updW2 + (size_t)l * 128 * 384;
        const float* ub2 = updb2 + (size_t)l * 384;

        float *Vold, *Vnew, *Vbold, *Vbnew;
        if (l == 0)      { Vold = Va; Vnew = Vb;   Vbold = Vba; Vbnew = Vbb; }
        else if (l == 1) { Vold = Vb; Vnew = Va;   Vbold = Vbb; Vbnew = Vba; }
        else             { Vold = Va; Vnew = Vout; Vbold = Vba; Vbnew = Vbb; }

        // phi = silu([H|Sbar] @ W1 + b1) @ W2 + b2
        concat_kernel<<<(NN * 256 + 255) / 256, 256, 0, stream>>>(H, Sbar, Scat);
        {
            dim3 g(256 / 64, (NN + 63) / 64);
            gemm_kernel<1><<<g, 256, 0, stream>>>(Scat, W1, b1, X1, NN, 256, 256);
        }
        {
            dim3 g(640 / 64, (NN + 63) / 64);
            gemm_kernel<0><<<g, 256, 0, stream>>>(X1, W2, b2, phi, NN, 256, 640);
        }

        // message gather
        gather_kernel<<<NN, 128, 0, stream>>>(offsets, eidx, nbr, unit, rbf, env,
                                              phi, dW, db, Vold, Vbold,
                                              H, Sbar, Vnew, Vbnew);

        // u_v, v_v, v_norm, dot
        uv_kernel<<<(NN + 3) / 4, 128, 0, stream>>>(Vnew, Ul, Vl, u_v, vnorm, dotb);

        // a = silu([H|v_norm] @ uW1 + ub1) @ uW2 + ub2
        concat_kernel<<<(NN * 256 + 255) / 256, 256, 0, stream>>>(H, vnorm, Scat);
        {
            dim3 g(128 / 64, (NN + 63) / 64);
            gemm_kernel<1><<<g, 256, 0, stream>>>(Scat, uW1, ub1, X1, NN, 256, 128);
        }
        {
            dim3 g(384 / 64, (NN + 63) / 64);
            gemm_kernel<0><<<g, 256, 0, stream>>>(X1, uW2, ub2, abuf, NN, 128, 384);
        }

        // H += a1*dot + a2 ; Vnew += a0*u_v
        final_update_kernel<<<(NN * 128 + 255) / 256, 256, 0, stream>>>(abuf, dotb, u_v,
                                                                        H, Vnew);
    }
}

// Round 2
// 1463.889 us; speedup vs baseline: 1.0687x; 1.0687x over previous
//
#include <hip/hip_runtime.h>
#include <math.h>

#define NN 10000
#define NE 160000
#define FDIM 128
#define NRBF 20
#define PI_F 3.14159265358979323846f

// ---------------------------------------------------------------------------
// Edge geometry + src histogram (by original edge index)
// ---------------------------------------------------------------------------
__global__ void edge_geom_kernel(const float* __restrict__ xyz, const int* __restrict__ nbr,
                                 float* __restrict__ unit, float* __restrict__ rbf,
                                 float* __restrict__ env, int* __restrict__ counts)
{
    int e = blockIdx.x * blockDim.x + threadIdx.x;
    if (e >= NE) return;
    int s = nbr[2 * e], d = nbr[2 * e + 1];
    float dx = xyz[3 * d + 0] - xyz[3 * s + 0];
    float dy = xyz[3 * d + 1] - xyz[3 * s + 1];
    float dz = xyz[3 * d + 2] - xyz[3 * s + 2];
    float dist = sqrtf(dx * dx + dy * dy + dz * dz);
    float inv = 1.0f / dist;
    unit[3 * e + 0] = dx * inv;
    unit[3 * e + 1] = dy * inv;
    unit[3 * e + 2] = dz * inv;
    const float c = PI_F / 5.0f;
#pragma unroll
    for (int k = 0; k < NRBF; k++)
        rbf[NRBF * e + k] = sinf((float)(k + 1) * c * dist) * inv;
    env[e] = (dist < 5.0f) ? 0.5f * (cosf(c * dist) + 1.0f) : 0.0f;
    atomicAdd(&counts[s], 1);
}

// ---------------------------------------------------------------------------
// Single-block exclusive scan over counts -> offsets (N+1)
// ---------------------------------------------------------------------------
__global__ void scan_kernel(const int* __restrict__ counts, int* __restrict__ offsets)
{
    __shared__ int sd[1024];
    __shared__ int carry;
    if (threadIdx.x == 0) carry = 0;
    __syncthreads();
    for (int base = 0; base < NN; base += 1024) {
        int i = base + threadIdx.x;
        int v = (i < NN) ? counts[i] : 0;
        sd[threadIdx.x] = v;
        __syncthreads();
        for (int off = 1; off < 1024; off <<= 1) {
            int t = (threadIdx.x >= off) ? sd[threadIdx.x - off] : 0;
            __syncthreads();
            sd[threadIdx.x] += t;
            __syncthreads();
        }
        if (i < NN) offsets[i] = carry + sd[threadIdx.x] - v;
        __syncthreads();
        if (threadIdx.x == 0) carry += sd[1023];
        __syncthreads();
    }
    if (threadIdx.x == 0) offsets[NN] = carry;
}

// ---------------------------------------------------------------------------
// Permute edge data into CSR (src-grouped) order.
// ---------------------------------------------------------------------------
__global__ void fill_kernel(const int* __restrict__ nbr, const int* __restrict__ offsets,
                            int* __restrict__ cnt2,
                            const float* __restrict__ unit_in, const float* __restrict__ rbf_in,
                            const float* __restrict__ env_in,
                            int* __restrict__ dstP, float* __restrict__ unitP,
                            float* __restrict__ rbfP, float* __restrict__ envP)
{
    int e = blockIdx.x * blockDim.x + threadIdx.x;
    if (e >= NE) return;
    int s = nbr[2 * e];
    int p = offsets[s] + atomicAdd(&cnt2[s], 1);
    dstP[p] = nbr[2 * e + 1];
    envP[p] = env_in[e];
    unitP[3 * p + 0] = unit_in[3 * e + 0];
    unitP[3 * p + 1] = unit_in[3 * e + 1];
    unitP[3 * p + 2] = unit_in[3 * e + 2];
#pragma unroll
    for (int k = 0; k < NRBF; k++)
        rbfP[NRBF * p + k] = rbf_in[NRBF * e + k];
}

// ---------------------------------------------------------------------------
// fp32 GEMM: C[M,N] = act(A[M,K] @ W[K,N] + bias[N]); ACT=1 -> silu
// BM=BN=64, BK=16, 256 threads, 4x4 micro-tile.
// ---------------------------------------------------------------------------
template <int ACT>
__global__ __launch_bounds__(256) void gemm_kernel(const float* __restrict__ A,
                                                   const float* __restrict__ W,
                                                   const float* __restrict__ bias,
                                                   float* __restrict__ C,
                                                   int M, int K, int N)
{
    __shared__ __align__(16) float As[16][68];
    __shared__ __align__(16) float Ws[16][64];
    int tid = threadIdx.x;
    int tx = tid & 15, ty = tid >> 4;
    int row0 = blockIdx.y * 64, col0 = blockIdx.x * 64;
    float acc[4][4] = {};
    int la_r = tid >> 2;
    int la_c = (tid & 3) * 4;
    int lw_r = tid >> 4;
    int lw_c = (tid & 15) * 4;

    for (int k0 = 0; k0 < K; k0 += 16) {
        int ar = row0 + la_r;
        float4 av = make_float4(0.f, 0.f, 0.f, 0.f);
        if (ar < M) av = *(const float4*)&A[(size_t)ar * K + k0 + la_c];
        As[la_c + 0][la_r] = av.x;
        As[la_c + 1][la_r] = av.y;
        As[la_c + 2][la_r] = av.z;
        As[la_c + 3][la_r] = av.w;
        float4 wv = *(const float4*)&W[(size_t)(k0 + lw_r) * N + col0 + lw_c];
        *(float4*)&Ws[lw_r][lw_c] = wv;
        __syncthreads();
#pragma unroll
        for (int k = 0; k < 16; k++) {
            float ar4[4], wr4[4];
#pragma unroll
            for (int i = 0; i < 4; i++) ar4[i] = As[k][ty * 4 + i];
#pragma unroll
            for (int j = 0; j < 4; j++) wr4[j] = Ws[k][tx * 4 + j];
#pragma unroll
            for (int i = 0; i < 4; i++)
#pragma unroll
                for (int j = 0; j < 4; j++) acc[i][j] += ar4[i] * wr4[j];
        }
        __syncthreads();
    }
#pragma unroll
    for (int i = 0; i < 4; i++) {
        int r = row0 + ty * 4 + i;
        if (r >= M) continue;
#pragma unroll
        for (int j = 0; j < 4; j++) {
            int c = col0 + tx * 4 + j;
            float v = acc[i][j] + bias[c];
            if (ACT) v = v / (1.0f + expf(-v));
            C[(size_t)r * N + c] = v;
        }
    }
}

// ---------------------------------------------------------------------------
// Same GEMM but A = concat(A0, A1) along columns; K fixed = 256 (128+128).
// ---------------------------------------------------------------------------
template <int ACT>
__global__ __launch_bounds__(256) void gemm_cat_kernel(const float* __restrict__ A0,
                                                       const float* __restrict__ A1,
                                                       const float* __restrict__ W,
                                                       const float* __restrict__ bias,
                                                       float* __restrict__ C,
                                                       int M, int N)
{
    __shared__ __align__(16) float As[16][68];
    __shared__ __align__(16) float Ws[16][64];
    int tid = threadIdx.x;
    int tx = tid & 15, ty = tid >> 4;
    int row0 = blockIdx.y * 64, col0 = blockIdx.x * 64;
    float acc[4][4] = {};
    int la_r = tid >> 2;
    int la_c = (tid & 3) * 4;
    int lw_r = tid >> 4;
    int lw_c = (tid & 15) * 4;

    for (int k0 = 0; k0 < 256; k0 += 16) {
        int ar = row0 + la_r;
        int col = k0 + la_c;
        float4 av = make_float4(0.f, 0.f, 0.f, 0.f);
        if (ar < M) {
            const float* src = (col < 128) ? &A0[(size_t)ar * 128 + col]
                                           : &A1[(size_t)ar * 128 + (col - 128)];
            av = *(const float4*)src;
        }
        As[la_c + 0][la_r] = av.x;
        As[la_c + 1][la_r] = av.y;
        As[la_c + 2][la_r] = av.z;
        As[la_c + 3][la_r] = av.w;
        float4 wv = *(const float4*)&W[(size_t)(k0 + lw_r) * N + col0 + lw_c];
        *(float4*)&Ws[lw_r][lw_c] = wv;
        __syncthreads();
#pragma unroll
        for (int k = 0; k < 16; k++) {
            float ar4[4], wr4[4];
#pragma unroll
            for (int i = 0; i < 4; i++) ar4[i] = As[k][ty * 4 + i];
#pragma unroll
            for (int j = 0; j < 4; j++) wr4[j] = Ws[k][tx * 4 + j];
#pragma unroll
            for (int i = 0; i < 4; i++)
#pragma unroll
                for (int j = 0; j < 4; j++) acc[i][j] += ar4[i] * wr4[j];
        }
        __syncthreads();
    }
#pragma unroll
    for (int i = 0; i < 4; i++) {
        int r = row0 + ty * 4 + i;
        if (r >= M) continue;
#pragma unroll
        for (int j = 0; j < 4; j++) {
            int c = col0 + tx * 4 + j;
            float v = acc[i][j] + bias[c];
            if (ACT) v = v / (1.0f + expf(-v));
            C[(size_t)r * N + c] = v;
        }
    }
}

// ---------------------------------------------------------------------------
// Gather message kernel: 256 threads = 2 nodes/block, 128 threads per node.
// dist_W columns hoisted into 100 registers/thread (loop-invariant).
// No LDS. Edge data read in CSR-permuted (sequential) order.
// ---------------------------------------------------------------------------
__global__ __launch_bounds__(256, 3) void gather_kernel(
    const int* __restrict__ offsets, const int* __restrict__ dstP,
    const float* __restrict__ unitP, const float* __restrict__ rbfP,
    const float* __restrict__ envP,
    const float* __restrict__ phi,
    const float* __restrict__ distW, const float* __restrict__ distb,
    const float* __restrict__ Vold, const float* __restrict__ Vbold,
    float* __restrict__ H, float* __restrict__ Sbar,
    float* __restrict__ Vnew, float* __restrict__ Vbnew)
{
    int n = (blockIdx.x << 1) | (threadIdx.x >> 7);
    int f = threadIdx.x & 127;
    if (n >= NN) return;

    float w[5][NRBF];
#pragma unroll
    for (int k = 0; k < NRBF; k++) {
#pragma unroll
        for (int c = 0; c < 5; c++)
            w[c][k] = distW[k * 640 + c * 128 + f];
    }
    float b0 = distb[f], b1 = distb[128 + f], b2 = distb[256 + f],
          b3 = distb[384 + f], b4 = distb[512 + f];

    float accH = 0.f, accS = 0.f;
    float accV0 = 0.f, accV1 = 0.f, accV2 = 0.f;
    float accB0 = 0.f, accB1 = 0.f, accB2 = 0.f;
    int e0 = offsets[n], e1 = offsets[n + 1];
    for (int p = e0; p < e1; ++p) {
        int d = dstP[p];
        float ev = envP[p];
        float ux = unitP[3 * p + 0], uy = unitP[3 * p + 1], uz = unitP[3 * p + 2];
        float r[NRBF];
#pragma unroll
        for (int q = 0; q < NRBF / 4; q++) {
            float4 rv = *(const float4*)&rbfP[NRBF * p + 4 * q];
            r[4 * q + 0] = rv.x * ev;
            r[4 * q + 1] = rv.y * ev;
            r[4 * q + 2] = rv.z * ev;
            r[4 * q + 3] = rv.w * ev;
        }
        float w0 = b0 * ev, w1 = b1 * ev, w2 = b2 * ev, w3 = b3 * ev, w4 = b4 * ev;
#pragma unroll
        for (int k = 0; k < NRBF; k++) {
            float rk = r[k];
            w0 += rk * w[0][k];
            w1 += rk * w[1][k];
            w2 += rk * w[2][k];
            w3 += rk * w[3][k];
            w4 += rk * w[4][k];
        }
        const float* ph = &phi[(size_t)d * 640];
        float i0 = ph[f] * w0;
        float i1 = ph[128 + f] * w1;
        float i2 = ph[256 + f] * w2;
        float i3 = ph[384 + f] * w3;
        float i4 = ph[512 + f] * w4;
        accH += i1;
        accS += i3;
        const float* vd  = &Vold[(size_t)d * 384 + f * 3];
        const float* vbd = &Vbold[(size_t)d * 384 + f * 3];
        accV0 += i2 * ux + i0 * vd[0];
        accV1 += i2 * uy + i0 * vd[1];
        accV2 += i2 * uz + i0 * vd[2];
        accB0 += i2 * ux + i4 * vbd[0];
        accB1 += i2 * uy + i4 * vbd[1];
        accB2 += i2 * uz + i4 * vbd[2];
    }
    H[n * 128 + f] += accH;
    Sbar[n * 128 + f] += accS;
    const float* vo  = &Vold[(size_t)n * 384 + f * 3];
    const float* vbo = &Vbold[(size_t)n * 384 + f * 3];
    float* vn  = &Vnew[(size_t)n * 384 + f * 3];
    float* vbn = &Vbnew[(size_t)n * 384 + f * 3];
    vn[0] = vo[0] + accV0; vn[1] = vo[1] + accV1; vn[2] = vo[2] + accV2;
    vbn[0] = vbo[0] + accB0; vbn[1] = vbo[1] + accB1; vbn[2] = vbo[2] + accB2;
}

// ---------------------------------------------------------------------------
// u_v/v_v einsum + v_norm + dot.  4 nodes per block, 128 threads (g).
// ---------------------------------------------------------------------------
__global__ __launch_bounds__(128) void uv_kernel(const float* __restrict__ V,
                                                 const float* __restrict__ U,
                                                 const float* __restrict__ Vm,
                                                 float* __restrict__ u_v,
                                                 float* __restrict__ vnorm,
                                                 float* __restrict__ dotb)
{
    int g = threadIdx.x;
    int n0 = blockIdx.x * 4;
    __shared__ float sV[4 * 384];
    for (int i = g; i < 4 * 384; i += 128) {
        int nn = i / 384, rem = i % 384;
        int node = n0 + nn;
        sV[i] = (node < NN) ? V[(size_t)node * 384 + rem] : 0.f;
    }
    __syncthreads();
    float ua[4][3] = {}, va[4][3] = {};
    for (int ff = 0; ff < 128; ++ff) {
        float uf = U[ff * 128 + g];
        float vf = Vm[ff * 128 + g];
#pragma unroll
        for (int nn = 0; nn < 4; nn++) {
            float v0 = sV[nn * 384 + ff * 3 + 0];
            float v1 = sV[nn * 384 + ff * 3 + 1];
            float v2 = sV[nn * 384 + ff * 3 + 2];
            ua[nn][0] += v0 * uf; ua[nn][1] += v1 * uf; ua[nn][2] += v2 * uf;
            va[nn][0] += v0 * vf; va[nn][1] += v1 * vf; va[nn][2] += v2 * vf;
        }
    }
#pragma unroll
    for (int nn = 0; nn < 4; nn++) {
        int node = n0 + nn;
        if (node >= NN) continue;
        float d = ua[nn][0] * va[nn][0] + ua[nn][1] * va[nn][1] + ua[nn][2] * va[nn][2];
        float vn = sqrtf(va[nn][0] * va[nn][0] + va[nn][1] * va[nn][1] +
                         va[nn][2] * va[nn][2] + 1e-15f);
        u_v[(size_t)node * 384 + g * 3 + 0] = ua[nn][0];
        u_v[(size_t)node * 384 + g * 3 + 1] = ua[nn][1];
        u_v[(size_t)node * 384 + g * 3 + 2] = ua[nn][2];
        vnorm[node * 128 + g] = vn;
        dotb[node * 128 + g] = d;
    }
}

// ---------------------------------------------------------------------------
// Final per-layer update: H += a1*dot + a2 ; V += a0*u_v
// ---------------------------------------------------------------------------
__global__ void final_update_kernel(const float* __restrict__ a,
                                    const float* __restrict__ dotb,
                                    const float* __restrict__ u_v,
                                    float* __restrict__ H, float* __restrict__ Vbuf)
{
    int idx = blockIdx.x * blockDim.x + threadIdx.x;
    if (idx >= NN * 128) return;
    int n = idx >> 7, g = idx & 127;
    float a0 = a[n * 384 + g];
    float a1 = a[n * 384 + 128 + g];
    float a2 = a[n * 384 + 256 + g];
    H[idx] += a1 * dotb[idx] + a2;
    float* vp = &Vbuf[(size_t)n * 384 + g * 3];
    const float* up = &u_v[(size_t)n * 384 + g * 3];
    vp[0] += a0 * up[0];
    vp[1] += a0 * up[1];
    vp[2] += a0 * up[2];
}

// ---------------------------------------------------------------------------
extern "C" void kernel_launch(void* const* d_in, const int* in_sizes, int n_in,
                              void* d_out, int out_size, void* d_ws, size_t ws_size,
                              hipStream_t stream)
{
    const float* xyz    = (const float*)d_in[0];
    const int*   nbr    = (const int*)d_in[1];
    const float* H_in   = (const float*)d_in[3];
    const float* msgW1  = (const float*)d_in[4];
    const float* msgb1  = (const float*)d_in[5];
    const float* msgW2  = (const float*)d_in[6];
    const float* msgb2  = (const float*)d_in[7];
    const float* distW  = (const float*)d_in[8];
    const float* distb  = (const float*)d_in[9];
    const float* updU   = (const float*)d_in[10];
    const float* updV   = (const float*)d_in[11];
    const float* updW1  = (const float*)d_in[12];
    const float* updb1  = (const float*)d_in[13];
    const float* updW2  = (const float*)d_in[14];
    const float* updb2  = (const float*)d_in[15];

    float* out  = (float*)d_out;
    float* H    = out;                 // N*128
    float* Vout = out + NN * 128;      // N*384

    // ---- workspace carve (floats) ----
    float* f = (float*)d_ws;
    float* Va   = f; f += NN * 384;
    float* Vb   = f; f += NN * 384;
    float* Vba  = f; f += NN * 384;
    float* Vbb  = f; f += NN * 384;
    float* Sbar = f; f += NN * 128;
    float* X1   = f; f += NN * 256;
    float* phi  = f; f += NN * 640;
    float* u_v  = f; f += NN * 384;
    float* unit = f; f += NE * 3;
    float* rbf  = f; f += NE * NRBF;
    float* env  = f; f += NE;
    float* unitP = f; f += NE * 3;
    float* rbfP  = f; f += NE * NRBF;
    float* envP  = f; f += NE;
    int* ip = (int*)f;
    int* counts  = ip; ip += NN;
    int* offsets = ip; ip += NN + 1;
    int* cnt2    = ip; ip += NN;
    int* dstP    = ip; ip += NE;
    // aliases into dead phi region (phi dead after gather each layer)
    float* vnorm = phi;
    float* dotb  = phi + NN * 128;
    float* abuf  = phi + NN * 256;     // N*384

    // ---- init ----
    hipMemsetAsync(counts, 0, NN * sizeof(int), stream);
    hipMemsetAsync(cnt2, 0, NN * sizeof(int), stream);
    hipMemsetAsync(Va, 0, (size_t)NN * 384 * sizeof(float), stream);
    hipMemsetAsync(Vba, 0, (size_t)NN * 384 * sizeof(float), stream);
    hipMemsetAsync(Sbar, 0, (size_t)NN * 128 * sizeof(float), stream);
    hipMemcpyAsync(H, H_in, (size_t)NN * 128 * sizeof(float),
                   hipMemcpyDeviceToDevice, stream);

    // ---- edge geometry + CSR permutation ----
    edge_geom_kernel<<<(NE + 255) / 256, 256, 0, stream>>>(xyz, nbr, unit, rbf, env, counts);
    scan_kernel<<<1, 1024, 0, stream>>>(counts, offsets);
    fill_kernel<<<(NE + 255) / 256, 256, 0, stream>>>(nbr, offsets, cnt2,
                                                      unit, rbf, env,
                                                      dstP, unitP, rbfP, envP);

    for (int l = 0; l < 3; ++l) {
        const float* W1 = msgW1 + (size_t)l * 256 * 256;
        const float* b1 = msgb1 + (size_t)l * 256;
        const float* W2 = msgW2 + (size_t)l * 256 * 640;
        const float* b2 = msgb2 + (size_t)l * 640;
        const float* dW = distW + (size_t)l * NRBF * 640;
        const float* db = distb + (size_t)l * 640;
        const float* Ul = updU + (size_t)l * 128 * 128;
        const float* Vl = updV + (size_t)l * 128 * 128;
        const float* uW1 = updW1 + (size_t)l * 256 * 128;
        const float* ub1 = updb1 + (size_t)l * 128;
        const float* uW2 = updW2 + (size_t)l * 128 * 384;
        const float* ub2 = updb2 + (size_t)l * 384;

        float *Vold, *Vnew, *Vbold, *Vbnew;
        if (l == 0)      { Vold = Va; Vnew = Vb;   Vbold = Vba; Vbnew = Vbb; }
        else if (l == 1) { Vold = Vb; Vnew = Va;   Vbold = Vbb; Vbnew = Vba; }
        else             { Vold = Va; Vnew = Vout; Vbold = Vba; Vbnew = Vbb; }

        // phi = silu([H|Sbar] @ W1 + b1) @ W2 + b2
        {
            dim3 g(256 / 64, (NN + 63) / 64);
            gemm_cat_kernel<1><<<g, 256, 0, stream>>>(H, Sbar, W1, b1, X1, NN, 256);
        }
        {
            dim3 g(640 / 64, (NN + 63) / 64);
            gemm_kernel<0><<<g, 256, 0, stream>>>(X1, W2, b2, phi, NN, 256, 640);
        }

        // message gather (2 nodes per 256-thread block)
        gather_kernel<<<NN / 2, 256, 0, stream>>>(offsets, dstP, unitP, rbfP, envP,
                                                  phi, dW, db, Vold, Vbold,
                                                  H, Sbar, Vnew, Vbnew);

        // u_v, v_v, v_norm, dot
        uv_kernel<<<(NN + 3) / 4, 128, 0, stream>>>(Vnew, Ul, Vl, u_v, vnorm, dotb);

        // a = silu([H|v_norm] @ uW1 + ub1) @ uW2 + ub2
        {
            dim3 g(128 / 64, (NN + 63) / 64);
            gemm_cat_kernel<1><<<g, 256, 0, stream>>>(H, vnorm, uW1, ub1, X1, NN, 128);
        }
        {
            dim3 g(384 / 64, (NN + 63) / 64);
            gemm_kernel<0><<<g, 256, 0, stream>>>(X1, uW2, ub2, abuf, NN, 128, 384);
        }

        // H += a1*dot + a2 ; Vnew += a0*u_v
        final_update_kernel<<<(NN * 128 + 255) / 256, 256, 0, stream>>>(abuf, dotb, u_v,
                                                                        H, Vnew);
    }
}

// Round 4
// 1278.254 us; speedup vs baseline: 1.2239x; 1.1452x over previous
//
#include <hip/hip_runtime.h>
#include <math.h>

#define NN 10000
#define NE 160000
#define FDIM 128
#define NRBF 20
#define PI_F 3.14159265358979323846f

typedef float v2f __attribute__((ext_vector_type(2)));

// ---------------------------------------------------------------------------
// Pass 1: src histogram
// ---------------------------------------------------------------------------
__global__ void edge_count_kernel(const int* __restrict__ nbr, int* __restrict__ counts)
{
    int e = blockIdx.x * blockDim.x + threadIdx.x;
    if (e >= NE) return;
    atomicAdd(&counts[nbr[2 * e]], 1);
}

// ---------------------------------------------------------------------------
// Single-block exclusive scan over counts -> offsets (N+1)
// ---------------------------------------------------------------------------
__global__ void scan_kernel(const int* __restrict__ counts, int* __restrict__ offsets)
{
    __shared__ int sd[1024];
    __shared__ int carry;
    if (threadIdx.x == 0) carry = 0;
    __syncthreads();
    for (int base = 0; base < NN; base += 1024) {
        int i = base + threadIdx.x;
        int v = (i < NN) ? counts[i] : 0;
        sd[threadIdx.x] = v;
        __syncthreads();
        for (int off = 1; off < 1024; off <<= 1) {
            int t = (threadIdx.x >= off) ? sd[threadIdx.x - off] : 0;
            __syncthreads();
            sd[threadIdx.x] += t;
            __syncthreads();
        }
        if (i < NN) offsets[i] = carry + sd[threadIdx.x] - v;
        __syncthreads();
        if (threadIdx.x == 0) carry += sd[1023];
        __syncthreads();
    }
    if (threadIdx.x == 0) offsets[NN] = carry;
}

// ---------------------------------------------------------------------------
// Pass 2: compute geometry, write directly into CSR-permuted slots (fp32).
// ---------------------------------------------------------------------------
__global__ void edge_geom_fill_kernel(const float* __restrict__ xyz, const int* __restrict__ nbr,
                                      const int* __restrict__ offsets, int* __restrict__ cnt2,
                                      int* __restrict__ dstP, float* __restrict__ unitP,
                                      float* __restrict__ envP, float* __restrict__ rbfP)
{
    int e = blockIdx.x * blockDim.x + threadIdx.x;
    if (e >= NE) return;
    int s = nbr[2 * e], d = nbr[2 * e + 1];
    float dx = xyz[3 * d + 0] - xyz[3 * s + 0];
    float dy = xyz[3 * d + 1] - xyz[3 * s + 1];
    float dz = xyz[3 * d + 2] - xyz[3 * s + 2];
    float dist = sqrtf(dx * dx + dy * dy + dz * dz);
    float inv = 1.0f / dist;
    int p = offsets[s] + atomicAdd(&cnt2[s], 1);
    dstP[p] = d;
    unitP[3 * p + 0] = dx * inv;
    unitP[3 * p + 1] = dy * inv;
    unitP[3 * p + 2] = dz * inv;
    const float c = PI_F / 5.0f;
    envP[p] = (dist < 5.0f) ? 0.5f * (cosf(c * dist) + 1.0f) : 0.0f;
#pragma unroll
    for (int k = 0; k < NRBF; k++)
        rbfP[NRBF * p + k] = sinf((float)(k + 1) * c * dist) * inv;
}

// ---------------------------------------------------------------------------
// fp32 GEMM: C[M,N] = act(A[M,K] @ W[K,N] + bias[N]); ACT=1 -> silu
// ---------------------------------------------------------------------------
template <int ACT>
__global__ __launch_bounds__(256) void gemm_kernel(const float* __restrict__ A,
                                                   const float* __restrict__ W,
                                                   const float* __restrict__ bias,
                                                   float* __restrict__ C,
                                                   int M, int K, int N)
{
    __shared__ __align__(16) float As[16][68];
    __shared__ __align__(16) float Ws[16][64];
    int tid = threadIdx.x;
    int tx = tid & 15, ty = tid >> 4;
    int row0 = blockIdx.y * 64, col0 = blockIdx.x * 64;
    float acc[4][4] = {};
    int la_r = tid >> 2;
    int la_c = (tid & 3) * 4;
    int lw_r = tid >> 4;
    int lw_c = (tid & 15) * 4;

    for (int k0 = 0; k0 < K; k0 += 16) {
        int ar = row0 + la_r;
        float4 av = make_float4(0.f, 0.f, 0.f, 0.f);
        if (ar < M) av = *(const float4*)&A[(size_t)ar * K + k0 + la_c];
        As[la_c + 0][la_r] = av.x;
        As[la_c + 1][la_r] = av.y;
        As[la_c + 2][la_r] = av.z;
        As[la_c + 3][la_r] = av.w;
        float4 wv = *(const float4*)&W[(size_t)(k0 + lw_r) * N + col0 + lw_c];
        *(float4*)&Ws[lw_r][lw_c] = wv;
        __syncthreads();
#pragma unroll
        for (int k = 0; k < 16; k++) {
            float ar4[4], wr4[4];
#pragma unroll
            for (int i = 0; i < 4; i++) ar4[i] = As[k][ty * 4 + i];
#pragma unroll
            for (int j = 0; j < 4; j++) wr4[j] = Ws[k][tx * 4 + j];
#pragma unroll
            for (int i = 0; i < 4; i++)
#pragma unroll
                for (int j = 0; j < 4; j++) acc[i][j] += ar4[i] * wr4[j];
        }
        __syncthreads();
    }
#pragma unroll
    for (int i = 0; i < 4; i++) {
        int r = row0 + ty * 4 + i;
        if (r >= M) continue;
#pragma unroll
        for (int j = 0; j < 4; j++) {
            int c = col0 + tx * 4 + j;
            float v = acc[i][j] + bias[c];
            if (ACT) v = v / (1.0f + expf(-v));
            C[(size_t)r * N + c] = v;
        }
    }
}

// ---------------------------------------------------------------------------
// Same GEMM but A = concat(A0, A1) along columns; K fixed = 256 (128+128).
// ---------------------------------------------------------------------------
template <int ACT>
__global__ __launch_bounds__(256) void gemm_cat_kernel(const float* __restrict__ A0,
                                                       const float* __restrict__ A1,
                                                       const float* __restrict__ W,
                                                       const float* __restrict__ bias,
                                                       float* __restrict__ C,
                                                       int M, int N)
{
    __shared__ __align__(16) float As[16][68];
    __shared__ __align__(16) float Ws[16][64];
    int tid = threadIdx.x;
    int tx = tid & 15, ty = tid >> 4;
    int row0 = blockIdx.y * 64, col0 = blockIdx.x * 64;
    float acc[4][4] = {};
    int la_r = tid >> 2;
    int la_c = (tid & 3) * 4;
    int lw_r = tid >> 4;
    int lw_c = (tid & 15) * 4;

    for (int k0 = 0; k0 < 256; k0 += 16) {
        int ar = row0 + la_r;
        int col = k0 + la_c;
        float4 av = make_float4(0.f, 0.f, 0.f, 0.f);
        if (ar < M) {
            const float* src = (col < 128) ? &A0[(size_t)ar * 128 + col]
                                           : &A1[(size_t)ar * 128 + (col - 128)];
            av = *(const float4*)src;
        }
        As[la_c + 0][la_r] = av.x;
        As[la_c + 1][la_r] = av.y;
        As[la_c + 2][la_r] = av.z;
        As[la_c + 3][la_r] = av.w;
        float4 wv = *(const float4*)&W[(size_t)(k0 + lw_r) * N + col0 + lw_c];
        *(float4*)&Ws[lw_r][lw_c] = wv;
        __syncthreads();
#pragma unroll
        for (int k = 0; k < 16; k++) {
            float ar4[4], wr4[4];
#pragma unroll
            for (int i = 0; i < 4; i++) ar4[i] = As[k][ty * 4 + i];
#pragma unroll
            for (int j = 0; j < 4; j++) wr4[j] = Ws[k][tx * 4 + j];
#pragma unroll
            for (int i = 0; i < 4; i++)
#pragma unroll
                for (int j = 0; j < 4; j++) acc[i][j] += ar4[i] * wr4[j];
        }
        __syncthreads();
    }
#pragma unroll
    for (int i = 0; i < 4; i++) {
        int r = row0 + ty * 4 + i;
        if (r >= M) continue;
#pragma unroll
        for (int j = 0; j < 4; j++) {
            int c = col0 + tx * 4 + j;
            float v = acc[i][j] + bias[c];
            if (ACT) v = v / (1.0f + expf(-v));
            C[(size_t)r * N + c] = v;
        }
    }
}

// ---------------------------------------------------------------------------
// Gather message kernel: 256 threads = 2 nodes/block, 128 threads per node.
// dist_W held in 50 packed-float2 registers (launch_bounds(256,2) -> 256 VGPR
// budget). All fp32. V/Vbar in PLANAR layout: node n plane c at n*384+c*128+f
// (stride-1 coalesced for both the scattered dst reads and the src writes).
// ---------------------------------------------------------------------------
__global__ __launch_bounds__(256, 2) void gather_kernel(
    const int* __restrict__ offsets, const int* __restrict__ dstP,
    const float* __restrict__ unitP, const float* __restrict__ rbfP,
    const float* __restrict__ envP,
    const float* __restrict__ phi,
    const float* __restrict__ distW, const float* __restrict__ distb,
    const float* __restrict__ Vold, const float* __restrict__ Vbold,
    float* __restrict__ H, float* __restrict__ Sbar,
    float* __restrict__ Vnew, float* __restrict__ Vbnew)
{
    int n = (blockIdx.x << 1) | (threadIdx.x >> 7);
    int f = threadIdx.x & 127;

    v2f wreg[5][10];
#pragma unroll
    for (int q = 0; q < 10; q++) {
#pragma unroll
        for (int c = 0; c < 5; c++) {
            wreg[c][q].x = distW[(2 * q) * 640 + c * 128 + f];
            wreg[c][q].y = distW[(2 * q + 1) * 640 + c * 128 + f];
        }
    }
    float b0 = distb[f], b1 = distb[128 + f], b2 = distb[256 + f],
          b3 = distb[384 + f], b4 = distb[512 + f];

    float accH = 0.f, accS = 0.f;
    float accV0 = 0.f, accV1 = 0.f, accV2 = 0.f;
    float accB0 = 0.f, accB1 = 0.f, accB2 = 0.f;
    int e0 = offsets[n], e1 = offsets[n + 1];
    for (int p = e0; p < e1; ++p) {
        int d = dstP[p];
        float ev = envP[p];
        float ux = unitP[3 * p + 0], uy = unitP[3 * p + 1], uz = unitP[3 * p + 2];
        const v2f* rp = (const v2f*)(rbfP + NRBF * p);
        v2f a0 = {0.f, 0.f}, a1 = {0.f, 0.f}, a2 = {0.f, 0.f}, a3 = {0.f, 0.f}, a4 = {0.f, 0.f};
#pragma unroll
        for (int q = 0; q < 10; q++) {
            v2f r2 = rp[q];
            a0 += r2 * wreg[0][q];
            a1 += r2 * wreg[1][q];
            a2 += r2 * wreg[2][q];
            a3 += r2 * wreg[3][q];
            a4 += r2 * wreg[4][q];
        }
        float w0 = (a0.x + a0.y + b0) * ev;
        float w1 = (a1.x + a1.y + b1) * ev;
        float w2 = (a2.x + a2.y + b2) * ev;
        float w3 = (a3.x + a3.y + b3) * ev;
        float w4 = (a4.x + a4.y + b4) * ev;

        const float* ph = phi + (size_t)d * 640;
        float i0 = ph[f] * w0;
        float i1 = ph[128 + f] * w1;
        float i2 = ph[256 + f] * w2;
        float i3 = ph[384 + f] * w3;
        float i4 = ph[512 + f] * w4;
        accH += i1;
        accS += i3;
        const float* vd  = Vold  + (size_t)d * 384;
        const float* vbd = Vbold + (size_t)d * 384;
        accV0 += i2 * ux + i0 * vd[f];
        accV1 += i2 * uy + i0 * vd[128 + f];
        accV2 += i2 * uz + i0 * vd[256 + f];
        accB0 += i2 * ux + i4 * vbd[f];
        accB1 += i2 * uy + i4 * vbd[128 + f];
        accB2 += i2 * uz + i4 * vbd[256 + f];
    }
    H[n * 128 + f] += accH;
    Sbar[n * 128 + f] += accS;
    const float* vo  = Vold  + (size_t)n * 384;
    const float* vbo = Vbold + (size_t)n * 384;
    float* vn  = Vnew  + (size_t)n * 384;
    float* vbn = Vbnew + (size_t)n * 384;
    vn[f]       = vo[f]       + accV0;
    vn[128 + f] = vo[128 + f] + accV1;
    vn[256 + f] = vo[256 + f] + accV2;
    vbn[f]       = vbo[f]       + accB0;
    vbn[128 + f] = vbo[128 + f] + accB1;
    vbn[256 + f] = vbo[256 + f] + accB2;
}

// ---------------------------------------------------------------------------
// u_v/v_v einsum + v_norm + dot.  4 nodes per block, 128 threads (g).
// V and u_v in planar layout.
// ---------------------------------------------------------------------------
__global__ __launch_bounds__(128) void uv_kernel(const float* __restrict__ V,
                                                 const float* __restrict__ U,
                                                 const float* __restrict__ Vm,
                                                 float* __restrict__ u_v,
                                                 float* __restrict__ vnorm,
                                                 float* __restrict__ dotb)
{
    int g = threadIdx.x;
    int n0 = blockIdx.x * 4;
    __shared__ float sV[4 * 384];
    for (int i = g; i < 4 * 384; i += 128) {
        int nn = i / 384, rem = i % 384;
        int node = n0 + nn;
        sV[i] = (node < NN) ? V[(size_t)node * 384 + rem] : 0.f;
    }
    __syncthreads();
    float ua[4][3] = {}, va[4][3] = {};
    for (int ff = 0; ff < 128; ++ff) {
        float uf = U[ff * 128 + g];
        float vf = Vm[ff * 128 + g];
#pragma unroll
        for (int nn = 0; nn < 4; nn++) {
            float v0 = sV[nn * 384 + ff];
            float v1 = sV[nn * 384 + 128 + ff];
            float v2 = sV[nn * 384 + 256 + ff];
            ua[nn][0] += v0 * uf; ua[nn][1] += v1 * uf; ua[nn][2] += v2 * uf;
            va[nn][0] += v0 * vf; va[nn][1] += v1 * vf; va[nn][2] += v2 * vf;
        }
    }
#pragma unroll
    for (int nn = 0; nn < 4; nn++) {
        int node = n0 + nn;
        if (node >= NN) continue;
        float d = ua[nn][0] * va[nn][0] + ua[nn][1] * va[nn][1] + ua[nn][2] * va[nn][2];
        float vn = sqrtf(va[nn][0] * va[nn][0] + va[nn][1] * va[nn][1] +
                         va[nn][2] * va[nn][2] + 1e-15f);
        u_v[(size_t)node * 384 + g]       = ua[nn][0];
        u_v[(size_t)node * 384 + 128 + g] = ua[nn][1];
        u_v[(size_t)node * 384 + 256 + g] = ua[nn][2];
        vnorm[node * 128 + g] = vn;
        dotb[node * 128 + g] = d;
    }
}

// ---------------------------------------------------------------------------
// Final per-layer update: H += a1*dot + a2 ; V += a0*u_v.
// LAST=0: V stays planar in-place. LAST=1: write interleaved (n,f,3) to Vout.
// ---------------------------------------------------------------------------
template <int LAST>
__global__ void final_update_kernel(const float* __restrict__ a,
                                    const float* __restrict__ dotb,
                                    const float* __restrict__ u_v,
                                    float* __restrict__ H,
                                    float* __restrict__ Vplanar,
                                    float* __restrict__ Vout)
{
    int idx = blockIdx.x * blockDim.x + threadIdx.x;
    if (idx >= NN * 128) return;
    int n = idx >> 7, g = idx & 127;
    float a0 = a[n * 384 + g];
    float a1 = a[n * 384 + 128 + g];
    float a2 = a[n * 384 + 256 + g];
    H[idx] += a1 * dotb[idx] + a2;
    float* vp = Vplanar + (size_t)n * 384;
    const float* up = u_v + (size_t)n * 384;
    float v0 = vp[g]       + a0 * up[g];
    float v1 = vp[128 + g] + a0 * up[128 + g];
    float v2 = vp[256 + g] + a0 * up[256 + g];
    if (LAST) {
        float* o = Vout + (size_t)n * 384 + g * 3;
        o[0] = v0; o[1] = v1; o[2] = v2;
    } else {
        vp[g] = v0; vp[128 + g] = v1; vp[256 + g] = v2;
    }
}

// ---------------------------------------------------------------------------
extern "C" void kernel_launch(void* const* d_in, const int* in_sizes, int n_in,
                              void* d_out, int out_size, void* d_ws, size_t ws_size,
                              hipStream_t stream)
{
    const float* xyz    = (const float*)d_in[0];
    const int*   nbr    = (const int*)d_in[1];
    const float* H_in   = (const float*)d_in[3];
    const float* msgW1  = (const float*)d_in[4];
    const float* msgb1  = (const float*)d_in[5];
    const float* msgW2  = (const float*)d_in[6];
    const float* msgb2  = (const float*)d_in[7];
    const float* distW  = (const float*)d_in[8];
    const float* distb  = (const float*)d_in[9];
    const float* updU   = (const float*)d_in[10];
    const float* updV   = (const float*)d_in[11];
    const float* updW1  = (const float*)d_in[12];
    const float* updb1  = (const float*)d_in[13];
    const float* updW2  = (const float*)d_in[14];
    const float* updb2  = (const float*)d_in[15];

    float* out  = (float*)d_out;
    float* H    = out;                 // N*128
    float* Vout = out + NN * 128;      // N*384 interleaved (n,f,3)

    // ---- workspace carve (floats) ----
    float* f = (float*)d_ws;
    float* Va   = f; f += NN * 384;    // planar V buffers
    float* Vb   = f; f += NN * 384;
    float* Vba  = f; f += NN * 384;
    float* Vbb  = f; f += NN * 384;
    float* Sbar = f; f += NN * 128;
    float* X1   = f; f += NN * 256;
    float* phi  = f; f += NN * 640;
    float* u_v  = f; f += NN * 384;
    float* unitP = f; f += NE * 3;
    float* envP  = f; f += NE;
    float* rbfP  = f; f += NE * NRBF;
    int* ip = (int*)f;
    int* counts  = ip; ip += NN;
    int* offsets = ip; ip += NN + 1;
    int* cnt2    = ip; ip += NN;
    int* dstP    = ip; ip += NE;
    // aliases into dead phi region (phi dead after gather each layer)
    float* vnorm = phi;
    float* dotb  = phi + NN * 128;
    float* abuf  = phi + NN * 256;     // N*384

    // ---- init ----
    hipMemsetAsync(counts, 0, NN * sizeof(int), stream);
    hipMemsetAsync(cnt2, 0, NN * sizeof(int), stream);
    hipMemsetAsync(Va, 0, (size_t)NN * 384 * sizeof(float), stream);
    hipMemsetAsync(Vba, 0, (size_t)NN * 384 * sizeof(float), stream);
    hipMemsetAsync(Sbar, 0, (size_t)NN * 128 * sizeof(float), stream);
    hipMemcpyAsync(H, H_in, (size_t)NN * 128 * sizeof(float),
                   hipMemcpyDeviceToDevice, stream);

    // ---- edge CSR + geometry (2-pass, writes permuted directly) ----
    edge_count_kernel<<<(NE + 255) / 256, 256, 0, stream>>>(nbr, counts);
    scan_kernel<<<1, 1024, 0, stream>>>(counts, offsets);
    edge_geom_fill_kernel<<<(NE + 255) / 256, 256, 0, stream>>>(xyz, nbr, offsets, cnt2,
                                                                dstP, unitP, envP, rbfP);

    for (int l = 0; l < 3; ++l) {
        const float* W1 = msgW1 + (size_t)l * 256 * 256;
        const float* b1 = msgb1 + (size_t)l * 256;
        const float* W2 = msgW2 + (size_t)l * 256 * 640;
        const float* b2 = msgb2 + (size_t)l * 640;
        const float* dW = distW + (size_t)l * NRBF * 640;
        const float* db = distb + (size_t)l * 640;
        const float* Ul = updU + (size_t)l * 128 * 128;
        const float* Vl = updV + (size_t)l * 128 * 128;
        const float* uW1 = updW1 + (size_t)l * 256 * 128;
        const float* ub1 = updb1 + (size_t)l * 128;
        const float* uW2 = updW2 + (size_t)l * 128 * 384;
        const float* ub2 = updb2 + (size_t)l * 384;

        float *Vold, *Vnew, *Vbold, *Vbnew;
        if (l == 0)      { Vold = Va; Vnew = Vb; Vbold = Vba; Vbnew = Vbb; }
        else if (l == 1) { Vold = Vb; Vnew = Va; Vbold = Vbb; Vbnew = Vba; }
        else             { Vold = Va; Vnew = Vb; Vbold = Vba; Vbnew = Vbb; }

        // phi = silu([H|Sbar] @ W1 + b1) @ W2 + b2
        {
            dim3 g(256 / 64, (NN + 63) / 64);
            gemm_cat_kernel<1><<<g, 256, 0, stream>>>(H, Sbar, W1, b1, X1, NN, 256);
        }
        {
            dim3 g(640 / 64, (NN + 63) / 64);
            gemm_kernel<0><<<g, 256, 0, stream>>>(X1, W2, b2, phi, NN, 256, 640);
        }

        // message gather (2 nodes per 256-thread block)
        gather_kernel<<<NN / 2, 256, 0, stream>>>(offsets, dstP, unitP, rbfP, envP,
                                                  phi, dW, db, Vold, Vbold,
                                                  H, Sbar, Vnew, Vbnew);

        // u_v, v_v, v_norm, dot
        uv_kernel<<<(NN + 3) / 4, 128, 0, stream>>>(Vnew, Ul, Vl, u_v, vnorm, dotb);

        // a = silu([H|v_norm] @ uW1 + ub1) @ uW2 + ub2
        {
            dim3 g(128 / 64, (NN + 63) / 64);
            gemm_cat_kernel<1><<<g, 256, 0, stream>>>(H, vnorm, uW1, ub1, X1, NN, 128);
        }
        {
            dim3 g(384 / 64, (NN + 63) / 64);
            gemm_kernel<0><<<g, 256, 0, stream>>>(X1, uW2, ub2, abuf, NN, 128, 384);
        }

        // H += a1*dot + a2 ; V += a0*u_v
        if (l < 2)
            final_update_kernel<0><<<(NN * 128 + 255) / 256, 256, 0, stream>>>(
                abuf, dotb, u_v, H, Vnew, nullptr);
        else
            final_update_kernel<1><<<(NN * 128 + 255) / 256, 256, 0, stream>>>(
                abuf, dotb, u_v, H, Vnew, Vout);
    }
}

// Round 5
// 1161.584 us; speedup vs baseline: 1.3468x; 1.1004x over previous
//
#include <hip/hip_runtime.h>
#include <math.h>

#define NN 10000
#define NE 160000
#define FDIM 128
#define NRBF 20
#define PI_F 3.14159265358979323846f

// ---------------------------------------------------------------------------
// Pass 1: src histogram
// ---------------------------------------------------------------------------
__global__ void edge_count_kernel(const int* __restrict__ nbr, int* __restrict__ counts)
{
    int e = blockIdx.x * blockDim.x + threadIdx.x;
    if (e >= NE) return;
    atomicAdd(&counts[nbr[2 * e]], 1);
}

// ---------------------------------------------------------------------------
// Single-block exclusive scan over counts -> offsets (N+1)
// ---------------------------------------------------------------------------
__global__ void scan_kernel(const int* __restrict__ counts, int* __restrict__ offsets)
{
    __shared__ int sd[1024];
    __shared__ int carry;
    if (threadIdx.x == 0) carry = 0;
    __syncthreads();
    for (int base = 0; base < NN; base += 1024) {
        int i = base + threadIdx.x;
        int v = (i < NN) ? counts[i] : 0;
        sd[threadIdx.x] = v;
        __syncthreads();
        for (int off = 1; off < 1024; off <<= 1) {
            int t = (threadIdx.x >= off) ? sd[threadIdx.x - off] : 0;
            __syncthreads();
            sd[threadIdx.x] += t;
            __syncthreads();
        }
        if (i < NN) offsets[i] = carry + sd[threadIdx.x] - v;
        __syncthreads();
        if (threadIdx.x == 0) carry += sd[1023];
        __syncthreads();
    }
    if (threadIdx.x == 0) offsets[NN] = carry;
}

// ---------------------------------------------------------------------------
// Pass 2: compute geometry, write directly into CSR-permuted slots (fp32).
// ueP: float4 {ux,uy,uz,env} per edge.
// ---------------------------------------------------------------------------
__global__ void edge_geom_fill_kernel(const float* __restrict__ xyz, const int* __restrict__ nbr,
                                      const int* __restrict__ offsets, int* __restrict__ cnt2,
                                      int* __restrict__ dstP, float4* __restrict__ ueP,
                                      float* __restrict__ rbfP)
{
    int e = blockIdx.x * blockDim.x + threadIdx.x;
    if (e >= NE) return;
    int s = nbr[2 * e], d = nbr[2 * e + 1];
    float dx = xyz[3 * d + 0] - xyz[3 * s + 0];
    float dy = xyz[3 * d + 1] - xyz[3 * s + 1];
    float dz = xyz[3 * d + 2] - xyz[3 * s + 2];
    float dist = sqrtf(dx * dx + dy * dy + dz * dz);
    float inv = 1.0f / dist;
    int p = offsets[s] + atomicAdd(&cnt2[s], 1);
    dstP[p] = d;
    const float c = PI_F / 5.0f;
    float env = (dist < 5.0f) ? 0.5f * (cosf(c * dist) + 1.0f) : 0.0f;
    ueP[p] = make_float4(dx * inv, dy * inv, dz * inv, env);
#pragma unroll
    for (int k = 0; k < NRBF; k++)
        rbfP[NRBF * p + k] = sinf((float)(k + 1) * c * dist) * inv;
}

// ---------------------------------------------------------------------------
// fp32 GEMM: C[M,N] = act(A[M,K] @ W[K,N] + bias[N]); ACT=1 -> silu
// ---------------------------------------------------------------------------
template <int ACT>
__global__ __launch_bounds__(256) void gemm_kernel(const float* __restrict__ A,
                                                   const float* __restrict__ W,
                                                   const float* __restrict__ bias,
                                                   float* __restrict__ C,
                                                   int M, int K, int N)
{
    __shared__ __align__(16) float As[16][68];
    __shared__ __align__(16) float Ws[16][64];
    int tid = threadIdx.x;
    int tx = tid & 15, ty = tid >> 4;
    int row0 = blockIdx.y * 64, col0 = blockIdx.x * 64;
    float acc[4][4] = {};
    int la_r = tid >> 2;
    int la_c = (tid & 3) * 4;
    int lw_r = tid >> 4;
    int lw_c = (tid & 15) * 4;

    for (int k0 = 0; k0 < K; k0 += 16) {
        int ar = row0 + la_r;
        float4 av = make_float4(0.f, 0.f, 0.f, 0.f);
        if (ar < M) av = *(const float4*)&A[(size_t)ar * K + k0 + la_c];
        As[la_c + 0][la_r] = av.x;
        As[la_c + 1][la_r] = av.y;
        As[la_c + 2][la_r] = av.z;
        As[la_c + 3][la_r] = av.w;
        float4 wv = *(const float4*)&W[(size_t)(k0 + lw_r) * N + col0 + lw_c];
        *(float4*)&Ws[lw_r][lw_c] = wv;
        __syncthreads();
#pragma unroll
        for (int k = 0; k < 16; k++) {
            float ar4[4], wr4[4];
#pragma unroll
            for (int i = 0; i < 4; i++) ar4[i] = As[k][ty * 4 + i];
#pragma unroll
            for (int j = 0; j < 4; j++) wr4[j] = Ws[k][tx * 4 + j];
#pragma unroll
            for (int i = 0; i < 4; i++)
#pragma unroll
                for (int j = 0; j < 4; j++) acc[i][j] += ar4[i] * wr4[j];
        }
        __syncthreads();
    }
#pragma unroll
    for (int i = 0; i < 4; i++) {
        int r = row0 + ty * 4 + i;
        if (r >= M) continue;
#pragma unroll
        for (int j = 0; j < 4; j++) {
            int c = col0 + tx * 4 + j;
            float v = acc[i][j] + bias[c];
            if (ACT) v = v / (1.0f + expf(-v));
            C[(size_t)r * N + c] = v;
        }
    }
}

// ---------------------------------------------------------------------------
// Same GEMM but A = concat(A0, A1) along columns; K fixed = 256 (128+128).
// ---------------------------------------------------------------------------
template <int ACT>
__global__ __launch_bounds__(256) void gemm_cat_kernel(const float* __restrict__ A0,
                                                       const float* __restrict__ A1,
                                                       const float* __restrict__ W,
                                                       const float* __restrict__ bias,
                                                       float* __restrict__ C,
                                                       int M, int N)
{
    __shared__ __align__(16) float As[16][68];
    __shared__ __align__(16) float Ws[16][64];
    int tid = threadIdx.x;
    int tx = tid & 15, ty = tid >> 4;
    int row0 = blockIdx.y * 64, col0 = blockIdx.x * 64;
    float acc[4][4] = {};
    int la_r = tid >> 2;
    int la_c = (tid & 3) * 4;
    int lw_r = tid >> 4;
    int lw_c = (tid & 15) * 4;

    for (int k0 = 0; k0 < 256; k0 += 16) {
        int ar = row0 + la_r;
        int col = k0 + la_c;
        float4 av = make_float4(0.f, 0.f, 0.f, 0.f);
        if (ar < M) {
            const float* src = (col < 128) ? &A0[(size_t)ar * 128 + col]
                                           : &A1[(size_t)ar * 128 + (col - 128)];
            av = *(const float4*)src;
        }
        As[la_c + 0][la_r] = av.x;
        As[la_c + 1][la_r] = av.y;
        As[la_c + 2][la_r] = av.z;
        As[la_c + 3][la_r] = av.w;
        float4 wv = *(const float4*)&W[(size_t)(k0 + lw_r) * N + col0 + lw_c];
        *(float4*)&Ws[lw_r][lw_c] = wv;
        __syncthreads();
#pragma unroll
        for (int k = 0; k < 16; k++) {
            float ar4[4], wr4[4];
#pragma unroll
            for (int i = 0; i < 4; i++) ar4[i] = As[k][ty * 4 + i];
#pragma unroll
            for (int j = 0; j < 4; j++) wr4[j] = Ws[k][tx * 4 + j];
#pragma unroll
            for (int i = 0; i < 4; i++)
#pragma unroll
                for (int j = 0; j < 4; j++) acc[i][j] += ar4[i] * wr4[j];
        }
        __syncthreads();
    }
#pragma unroll
    for (int i = 0; i < 4; i++) {
        int r = row0 + ty * 4 + i;
        if (r >= M) continue;
#pragma unroll
        for (int j = 0; j < 4; j++) {
            int c = col0 + tx * 4 + j;
            float v = acc[i][j] + bias[c];
            if (ACT) v = v / (1.0f + expf(-v));
            C[(size_t)r * N + c] = v;
        }
    }
}

// ---------------------------------------------------------------------------
// Gather message kernel: 256 threads = 2 nodes/block, 128 threads per node.
// dist_W held in 100 registers, pinned with an opaque asm def so the
// allocator cannot rematerialize the loads into the edge loop.
// V/Vbar planar per node: n*384 + c*128 + f.
// ---------------------------------------------------------------------------
__global__ __launch_bounds__(256, 2) void gather_kernel(
    const int* __restrict__ offsets, const int* __restrict__ dstP,
    const float4* __restrict__ ueP, const float* __restrict__ rbfP,
    const float* __restrict__ phi,
    const float* __restrict__ distW, const float* __restrict__ distb,
    const float* __restrict__ Vold, const float* __restrict__ Vbold,
    float* __restrict__ H, float* __restrict__ Sbar,
    float* __restrict__ Vnew, float* __restrict__ Vbnew)
{
    int n = (blockIdx.x << 1) | (threadIdx.x >> 7);
    int f = threadIdx.x & 127;

    // wv[k*5+c] = distW[k,c*128+f]
    float wv[100];
#pragma unroll
    for (int k = 0; k < NRBF; k++)
#pragma unroll
        for (int c = 0; c < 5; c++)
            wv[k * 5 + c] = distW[k * 640 + c * 128 + f];
    // Opaque def: forbids rematerialization of the loads inside the loop.
#pragma unroll
    for (int i = 0; i < 100; i++) asm volatile("" : "+v"(wv[i]));

    float b0 = distb[f], b1 = distb[128 + f], b2 = distb[256 + f],
          b3 = distb[384 + f], b4 = distb[512 + f];

    float accH = 0.f, accS = 0.f;
    float accV0 = 0.f, accV1 = 0.f, accV2 = 0.f;
    float accB0 = 0.f, accB1 = 0.f, accB2 = 0.f;
    int e0 = offsets[n], e1 = offsets[n + 1];
    for (int p = e0; p < e1; ++p) {
        int d = dstP[p];
        float4 ue = ueP[p];
        float r[NRBF];
#pragma unroll
        for (int q = 0; q < NRBF / 4; q++) {
            float4 rv = *(const float4*)&rbfP[NRBF * p + 4 * q];
            r[4 * q + 0] = rv.x; r[4 * q + 1] = rv.y;
            r[4 * q + 2] = rv.z; r[4 * q + 3] = rv.w;
        }
        float w0 = b0, w1 = b1, w2 = b2, w3 = b3, w4 = b4;
#pragma unroll
        for (int k = 0; k < NRBF; k++) {
            float rk = r[k];
            w0 += rk * wv[k * 5 + 0];
            w1 += rk * wv[k * 5 + 1];
            w2 += rk * wv[k * 5 + 2];
            w3 += rk * wv[k * 5 + 3];
            w4 += rk * wv[k * 5 + 4];
        }
        float ev = ue.w;
        const float* ph = phi + (size_t)d * 640;
        float i0 = ph[f] * w0 * ev;
        float i1 = ph[128 + f] * w1 * ev;
        float i2 = ph[256 + f] * w2 * ev;
        float i3 = ph[384 + f] * w3 * ev;
        float i4 = ph[512 + f] * w4 * ev;
        accH += i1;
        accS += i3;
        const float* vd  = Vold  + (size_t)d * 384;
        const float* vbd = Vbold + (size_t)d * 384;
        accV0 += i2 * ue.x + i0 * vd[f];
        accV1 += i2 * ue.y + i0 * vd[128 + f];
        accV2 += i2 * ue.z + i0 * vd[256 + f];
        accB0 += i2 * ue.x + i4 * vbd[f];
        accB1 += i2 * ue.y + i4 * vbd[128 + f];
        accB2 += i2 * ue.z + i4 * vbd[256 + f];
    }
    H[n * 128 + f] += accH;
    Sbar[n * 128 + f] += accS;
    const float* vo  = Vold  + (size_t)n * 384;
    const float* vbo = Vbold + (size_t)n * 384;
    float* vn  = Vnew  + (size_t)n * 384;
    float* vbn = Vbnew + (size_t)n * 384;
    vn[f]       = vo[f]       + accV0;
    vn[128 + f] = vo[128 + f] + accV1;
    vn[256 + f] = vo[256 + f] + accV2;
    vbn[f]       = vbo[f]       + accB0;
    vbn[128 + f] = vbo[128 + f] + accB1;
    vbn[256 + f] = vbo[256 + f] + accB2;
}

// ---------------------------------------------------------------------------
// u_v/v_v einsum + v_norm + dot.  4 nodes per block, 128 threads (g).
// V and u_v in planar layout.
// ---------------------------------------------------------------------------
__global__ __launch_bounds__(128) void uv_kernel(const float* __restrict__ V,
                                                 const float* __restrict__ U,
                                                 const float* __restrict__ Vm,
                                                 float* __restrict__ u_v,
                                                 float* __restrict__ vnorm,
                                                 float* __restrict__ dotb)
{
    int g = threadIdx.x;
    int n0 = blockIdx.x * 4;
    __shared__ float sV[4 * 384];
    for (int i = g; i < 4 * 384; i += 128) {
        int nn = i / 384, rem = i % 384;
        int node = n0 + nn;
        sV[i] = (node < NN) ? V[(size_t)node * 384 + rem] : 0.f;
    }
    __syncthreads();
    float ua[4][3] = {}, va[4][3] = {};
    for (int ff = 0; ff < 128; ++ff) {
        float uf = U[ff * 128 + g];
        float vf = Vm[ff * 128 + g];
#pragma unroll
        for (int nn = 0; nn < 4; nn++) {
            float v0 = sV[nn * 384 + ff];
            float v1 = sV[nn * 384 + 128 + ff];
            float v2 = sV[nn * 384 + 256 + ff];
            ua[nn][0] += v0 * uf; ua[nn][1] += v1 * uf; ua[nn][2] += v2 * uf;
            va[nn][0] += v0 * vf; va[nn][1] += v1 * vf; va[nn][2] += v2 * vf;
        }
    }
#pragma unroll
    for (int nn = 0; nn < 4; nn++) {
        int node = n0 + nn;
        if (node >= NN) continue;
        float d = ua[nn][0] * va[nn][0] + ua[nn][1] * va[nn][1] + ua[nn][2] * va[nn][2];
        float vn = sqrtf(va[nn][0] * va[nn][0] + va[nn][1] * va[nn][1] +
                         va[nn][2] * va[nn][2] + 1e-15f);
        u_v[(size_t)node * 384 + g]       = ua[nn][0];
        u_v[(size_t)node * 384 + 128 + g] = ua[nn][1];
        u_v[(size_t)node * 384 + 256 + g] = ua[nn][2];
        vnorm[node * 128 + g] = vn;
        dotb[node * 128 + g] = d;
    }
}

// ---------------------------------------------------------------------------
// Final per-layer update: H += a1*dot + a2 ; V += a0*u_v.
// LAST=0: V stays planar in-place. LAST=1: write interleaved (n,f,3) to Vout.
// ---------------------------------------------------------------------------
template <int LAST>
__global__ void final_update_kernel(const float* __restrict__ a,
                                    const float* __restrict__ dotb,
                                    const float* __restrict__ u_v,
                                    float* __restrict__ H,
                                    float* __restrict__ Vplanar,
                                    float* __restrict__ Vout)
{
    int idx = blockIdx.x * blockDim.x + threadIdx.x;
    if (idx >= NN * 128) return;
    int n = idx >> 7, g = idx & 127;
    float a0 = a[n * 384 + g];
    float a1 = a[n * 384 + 128 + g];
    float a2 = a[n * 384 + 256 + g];
    H[idx] += a1 * dotb[idx] + a2;
    float* vp = Vplanar + (size_t)n * 384;
    const float* up = u_v + (size_t)n * 384;
    float v0 = vp[g]       + a0 * up[g];
    float v1 = vp[128 + g] + a0 * up[128 + g];
    float v2 = vp[256 + g] + a0 * up[256 + g];
    if (LAST) {
        float* o = Vout + (size_t)n * 384 + g * 3;
        o[0] = v0; o[1] = v1; o[2] = v2;
    } else {
        vp[g] = v0; vp[128 + g] = v1; vp[256 + g] = v2;
    }
}

// ---------------------------------------------------------------------------
extern "C" void kernel_launch(void* const* d_in, const int* in_sizes, int n_in,
                              void* d_out, int out_size, void* d_ws, size_t ws_size,
                              hipStream_t stream)
{
    const float* xyz    = (const float*)d_in[0];
    const int*   nbr    = (const int*)d_in[1];
    const float* H_in   = (const float*)d_in[3];
    const float* msgW1  = (const float*)d_in[4];
    const float* msgb1  = (const float*)d_in[5];
    const float* msgW2  = (const float*)d_in[6];
    const float* msgb2  = (const float*)d_in[7];
    const float* distW  = (const float*)d_in[8];
    const float* distb  = (const float*)d_in[9];
    const float* updU   = (const float*)d_in[10];
    const float* updV   = (const float*)d_in[11];
    const float* updW1  = (const float*)d_in[12];
    const float* updb1  = (const float*)d_in[13];
    const float* updW2  = (const float*)d_in[14];
    const float* updb2  = (const float*)d_in[15];

    float* out  = (float*)d_out;
    float* H    = out;                 // N*128
    float* Vout = out + NN * 128;      // N*384 interleaved (n,f,3)

    // ---- workspace carve (floats) ----
    float* f = (float*)d_ws;
    float* Va   = f; f += NN * 384;    // planar V buffers
    float* Vb   = f; f += NN * 384;
    float* Vba  = f; f += NN * 384;
    float* Vbb  = f; f += NN * 384;
    float* Sbar = f; f += NN * 128;
    float* X1   = f; f += NN * 256;
    float* phi  = f; f += NN * 640;
    float* u_v  = f; f += NN * 384;
    float4* ueP = (float4*)f; f += NE * 4;
    float* rbfP  = f; f += NE * NRBF;
    int* ip = (int*)f;
    int* counts  = ip; ip += NN;
    int* offsets = ip; ip += NN + 1;
    int* cnt2    = ip; ip += NN;
    int* dstP    = ip; ip += NE;
    // aliases into dead phi region (phi dead after gather each layer)
    float* vnorm = phi;
    float* dotb  = phi + NN * 128;
    float* abuf  = phi + NN * 256;     // N*384

    // ---- init ----
    hipMemsetAsync(counts, 0, NN * sizeof(int), stream);
    hipMemsetAsync(cnt2, 0, NN * sizeof(int), stream);
    hipMemsetAsync(Va, 0, (size_t)NN * 384 * sizeof(float), stream);
    hipMemsetAsync(Vba, 0, (size_t)NN * 384 * sizeof(float), stream);
    hipMemsetAsync(Sbar, 0, (size_t)NN * 128 * sizeof(float), stream);
    hipMemcpyAsync(H, H_in, (size_t)NN * 128 * sizeof(float),
                   hipMemcpyDeviceToDevice, stream);

    // ---- edge CSR + geometry (2-pass, writes permuted directly) ----
    edge_count_kernel<<<(NE + 255) / 256, 256, 0, stream>>>(nbr, counts);
    scan_kernel<<<1, 1024, 0, stream>>>(counts, offsets);
    edge_geom_fill_kernel<<<(NE + 255) / 256, 256, 0, stream>>>(xyz, nbr, offsets, cnt2,
                                                                dstP, ueP, rbfP);

    for (int l = 0; l < 3; ++l) {
        const float* W1 = msgW1 + (size_t)l * 256 * 256;
        const float* b1 = msgb1 + (size_t)l * 256;
        const float* W2 = msgW2 + (size_t)l * 256 * 640;
        const float* b2 = msgb2 + (size_t)l * 640;
        const float* dW = distW + (size_t)l * NRBF * 640;
        const float* db = distb + (size_t)l * 640;
        const float* Ul = updU + (size_t)l * 128 * 128;
        const float* Vl = updV + (size_t)l * 128 * 128;
        const float* uW1 = updW1 + (size_t)l * 256 * 128;
        const float* ub1 = updb1 + (size_t)l * 128;
        const float* uW2 = updW2 + (size_t)l * 128 * 384;
        const float* ub2 = updb2 + (size_t)l * 384;

        float *Vold, *Vnew, *Vbold, *Vbnew;
        if (l == 0)      { Vold = Va; Vnew = Vb; Vbold = Vba; Vbnew = Vbb; }
        else if (l == 1) { Vold = Vb; Vnew = Va; Vbold = Vbb; Vbnew = Vba; }
        else             { Vold = Va; Vnew = Vb; Vbold = Vba; Vbnew = Vbb; }

        // phi = silu([H|Sbar] @ W1 + b1) @ W2 + b2
        {
            dim3 g(256 / 64, (NN + 63) / 64);
            gemm_cat_kernel<1><<<g, 256, 0, stream>>>(H, Sbar, W1, b1, X1, NN, 256);
        }
        {
            dim3 g(640 / 64, (NN + 63) / 64);
            gemm_kernel<0><<<g, 256, 0, stream>>>(X1, W2, b2, phi, NN, 256, 640);
        }

        // message gather (2 nodes per 256-thread block)
        gather_kernel<<<NN / 2, 256, 0, stream>>>(offsets, dstP, ueP, rbfP,
                                                  phi, dW, db, Vold, Vbold,
                                                  H, Sbar, Vnew, Vbnew);

        // u_v, v_v, v_norm, dot
        uv_kernel<<<(NN + 3) / 4, 128, 0, stream>>>(Vnew, Ul, Vl, u_v, vnorm, dotb);

        // a = silu([H|v_norm] @ uW1 + ub1) @ uW2 + ub2
        {
            dim3 g(128 / 64, (NN + 63) / 64);
            gemm_cat_kernel<1><<<g, 256, 0, stream>>>(H, vnorm, uW1, ub1, X1, NN, 128);
        }
        {
            dim3 g(384 / 64, (NN + 63) / 64);
            gemm_kernel<0><<<g, 256, 0, stream>>>(X1, uW2, ub2, abuf, NN, 128, 384);
        }

        // H += a1*dot + a2 ; V += a0*u_v
        if (l < 2)
            final_update_kernel<0><<<(NN * 128 + 255) / 256, 256, 0, stream>>>(
                abuf, dotb, u_v, H, Vnew, nullptr);
        else
            final_update_kernel<1><<<(NN * 128 + 255) / 256, 256, 0, stream>>>(
                abuf, dotb, u_v, H, Vnew, Vout);
    }
}